// Round 14
// baseline (122.917 us; speedup 1.0000x reference)
//
#include <hip/hip_runtime.h>
#include <hip/hip_bf16.h>
#include <stdint.h>

#define B_  2
#define S_  2048
#define H_  16
#define D_  64
#define HID 1024

typedef __bf16 bf16x8 __attribute__((ext_vector_type(8)));
typedef float  f32x4  __attribute__((ext_vector_type(4)));
typedef float  f32x16 __attribute__((ext_vector_type(16)));
typedef unsigned int u32x4 __attribute__((ext_vector_type(4)));
typedef unsigned short ush;

__device__ __forceinline__ ush f2bf(float f) {
    __bf16 b = (__bf16)f;
    return __builtin_bit_cast(ush, b);
}
__device__ __forceinline__ unsigned pk2(float a, float b) {
    return (unsigned)f2bf(a) | ((unsigned)f2bf(b) << 16);
}
__device__ __forceinline__ float xchg32f(float x) {
    return __shfl_xor(x, 32, 64);
}
__device__ __forceinline__ float exp2fast(float x) {
#if __has_builtin(__builtin_amdgcn_exp2f)
    return __builtin_amdgcn_exp2f(x);
#else
    float r; asm("v_exp_f32 %0, %1" : "=v"(r) : "v"(x)); return r;
#endif
}
__device__ __forceinline__ void gld16(const void* g, void* l) {
    __builtin_amdgcn_global_load_lds(
        (const __attribute__((address_space(1))) unsigned*)g,
        (__attribute__((address_space(3))) unsigned*)l, 16, 0, 0);
}
#define MFMA32(a, b, c) __builtin_amdgcn_mfma_f32_32x32x16_bf16(a, b, c, 0, 0, 0)

// ---------------- fused prep: hidden cvt (blocks 0..1023) + W transpose -----
__global__ __launch_bounds__(256) void prep(
    const float* __restrict__ hid, ush* __restrict__ hidb,
    const float* __restrict__ Wq, const float* __restrict__ Wk,
    const float* __restrict__ Wv, ush* __restrict__ wt)
{
    const int tid = threadIdx.x;
    __shared__ ush lT[64][72];

    if (blockIdx.x < 1024) {
        size_t base = ((size_t)blockIdx.x * 256 + tid) * 16;
        #pragma unroll
        for (int half = 0; half < 2; ++half) {
            float4 v0 = *reinterpret_cast<const float4*>(hid + base + half * 8);
            float4 v1 = *reinterpret_cast<const float4*>(hid + base + half * 8 + 4);
            u32x4 o = { pk2(v0.x, v0.y), pk2(v0.z, v0.w),
                        pk2(v1.x, v1.y), pk2(v1.z, v1.w) };
            *reinterpret_cast<u32x4*>(hidb + base + half * 8) = o;
        }
        return;
    }

    const int L = blockIdx.x - 1024;            // 0..767 = 16 x 16 x 3
    const int k0 = (L & 15) * 64, n0 = ((L >> 4) & 15) * 64, sel = L >> 8;
    const float* W = sel == 0 ? Wq : (sel == 1 ? Wk : Wv);
    ush* o = wt + (size_t)sel * HID * HID;
    #pragma unroll
    for (int i = 0; i < 4; ++i) {
        int c = tid + i * 256;
        int kr = c >> 4, c4 = (c & 15) << 2;
        float4 v = *reinterpret_cast<const float4*>(W + (size_t)(k0 + kr) * HID + n0 + c4);
        lT[kr][c4 + 0] = f2bf(v.x); lT[kr][c4 + 1] = f2bf(v.y);
        lT[kr][c4 + 2] = f2bf(v.z); lT[kr][c4 + 3] = f2bf(v.w);
    }
    __syncthreads();
    #pragma unroll
    for (int i = 0; i < 2; ++i) {
        int c = tid + i * 256;
        int nr = c >> 3, k8 = (c & 7) << 3;
        ush t[8];
        #pragma unroll
        for (int u = 0; u < 8; ++u) t[u] = lT[k8 + u][nr];
        u32x4 ov = { (unsigned)t[0] | ((unsigned)t[1] << 16),
                     (unsigned)t[2] | ((unsigned)t[3] << 16),
                     (unsigned)t[4] | ((unsigned)t[5] << 16),
                     (unsigned)t[6] | ((unsigned)t[7] << 16) };
        *reinterpret_cast<u32x4*>(o + (size_t)(n0 + nr) * HID + k0 + k8) = ov;
    }
}

// ---------------- fused QKV projection: C[4096][3072] = hid_bf @ Wt^T -------
// 128x128 tile, 4 waves (2x2), BK=64, global_load_lds + XOR-swizzled LDS.
__global__ __launch_bounds__(256) void proj(
    const ush* __restrict__ hidb, const ush* __restrict__ wt,
    const float* __restrict__ bq, const float* __restrict__ bk,
    const float* __restrict__ bv,
    ush* __restrict__ qd, ush* __restrict__ kd, ush* __restrict__ vtd)
{
    const int tid = threadIdx.x;
    const int wave = tid >> 6, lane = tid & 63;
    const int fr = lane & 15, fq = lane >> 4;
    const int wr = wave >> 1, wc = wave & 1;
    const int m0 = blockIdx.x * 128;
    const int n0 = blockIdx.y * 128;            // global col in [0,3072)
    const int wsel = n0 >> 10;

    __shared__ char pool[65536];   // lA: 0 + buf*16K ; lB: 32K + buf*16K ; lT aliases

    const int cr = lane >> 3;      // row within 8-row chunk
    const int cs = lane & 7;       // 16B slot within row

    f32x4 acc[4][4] = {};

    const ush* Asrc = hidb + (size_t)m0 * HID;
    const ush* Bsrc = wt + (size_t)n0 * HID;

    auto stage = [&](int buf, int kk) {
        #pragma unroll
        for (int j = 0; j < 4; ++j) {
            int ch = wave * 4 + j;
            int r = ch * 8 + cr;
            int so = kk + ((cs ^ (r & 7)) << 3);
            gld16(Asrc + (size_t)r * HID + so, pool + buf * 16384 + ch * 1024);
            gld16(Bsrc + (size_t)r * HID + so, pool + 32768 + buf * 16384 + ch * 1024);
        }
    };

    stage(0, 0);
    __syncthreads();
    int buf = 0;
    for (int ks = 0; ks < 16; ++ks) {
        if (ks < 15) stage(buf ^ 1, (ks + 1) * 64);
        const char* ab = pool + buf * 16384;
        const char* bb = pool + 32768 + buf * 16384;
        #pragma unroll
        for (int c = 0; c < 2; ++c) {
            bf16x8 a[4], b[4];
            #pragma unroll
            for (int i = 0; i < 4; ++i) {
                int ra = wr * 64 + i * 16 + fr;
                a[i] = *reinterpret_cast<const bf16x8*>(
                    ab + ((ra * 128 + c * 64 + fq * 16) ^ ((ra & 7) << 4)));
                int rb = wc * 64 + i * 16 + fr;
                b[i] = *reinterpret_cast<const bf16x8*>(
                    bb + ((rb * 128 + c * 64 + fq * 16) ^ ((rb & 7) << 4)));
            }
            __builtin_amdgcn_s_setprio(1);
            #pragma unroll
            for (int i = 0; i < 4; ++i)
                #pragma unroll
                for (int j = 0; j < 4; ++j)
                    acc[i][j] = __builtin_amdgcn_mfma_f32_16x16x32_bf16(
                        a[i], b[j], acc[i][j], 0, 0, 0);
            __builtin_amdgcn_s_setprio(0);
        }
        __syncthreads();
        buf ^= 1;
    }

    const int bi = m0 >> 11;
    const int s0 = m0 & 2047;
    const float* bias = wsel == 0 ? bq : (wsel == 1 ? bk : bv);
    const int nb = n0 & 1023;

    if (wsel < 2) {
        ush* dst = wsel == 0 ? qd : kd;
        // Q: fold 1/sqrt(64) AND log2(e) (attn works in exp2 domain)
        const float scale = wsel == 0 ? 0.18033688011112042f : 1.0f;
        #pragma unroll
        for (int j = 0; j < 4; ++j) {
            int n = nb + wc * 64 + j * 16 + fr;
            int hh = n >> 6, d = n & 63;
            float bb2 = bias[n];
            const size_t rowb = (size_t)(bi * H_ + hh) * S_;
            #pragma unroll
            for (int i = 0; i < 4; ++i)
                #pragma unroll
                for (int e = 0; e < 4; ++e) {
                    int s = s0 + wr * 64 + i * 16 + fq * 4 + e;
                    dst[(rowb + s) * D_ + d] = f2bf((acc[i][j][e] + bb2) * scale);
                }
        }
    } else {
        // V: bounce through LDS (aliases lA/lB), store transposed [B,H,D,S]
        ush (*lT)[136] = (ush (*)[136])pool;
        #pragma unroll
        for (int j = 0; j < 4; ++j) {
            int nl = wc * 64 + j * 16 + fr;
            float bb2 = bias[nb + nl];
            #pragma unroll
            for (int i = 0; i < 4; ++i)
                #pragma unroll
                for (int e = 0; e < 4; ++e)
                    lT[wr * 64 + i * 16 + fq * 4 + e][nl] = f2bf(acc[i][j][e] + bb2);
        }
        __syncthreads();
        #pragma unroll
        for (int c2 = 0; c2 < 8; ++c2) {
            int cid = tid + c2 * 256;          // 0..2047
            int nl = cid >> 4, s8 = (cid & 15) * 8;
            int n = nb + nl, hh = n >> 6, d = n & 63;
            ush t[8];
            #pragma unroll
            for (int u = 0; u < 8; ++u) t[u] = lT[s8 + u][nl];
            u32x4 ov = { (unsigned)t[0] | ((unsigned)t[1] << 16),
                         (unsigned)t[2] | ((unsigned)t[3] << 16),
                         (unsigned)t[4] | ((unsigned)t[5] << 16),
                         (unsigned)t[6] | ((unsigned)t[7] << 16) };
            *reinterpret_cast<u32x4*>(
                vtd + ((size_t)(bi * H_ + hh) * D_ + d) * S_ + s0 + s8) = ov;
        }
    }
}

// ---------------- flash attention v10 ----------------------------------------
// r13 structure with 256-kv supersteps: ping-pong SUPER-buffers (2 x 64KB =
// 4 x 32KB sub-buffers), COMP runs twice per superstep, ONE vmcnt(0)+barrier
// per 256 kv -> barrier count 16 -> 8, each stage gets ~2x compute of cover.
// Per-wave math/layout/order identical to r13 (absmax unchanged).
// 256 blocks (XCD decode), 512 thr = 8 waves = qsub(0..3) x parity(0..1).
#define STAGE(sb, kv0) do {                                                    \
    char* base_ = pool + (sb) * 32768;                                         \
    gld16(K + (size_t)((kv0) + kr) * D_ + ss,      base_ + wave * 1024);       \
    gld16(K + (size_t)((kv0) + 64 + kr) * D_ + ss, base_ + 8192 + wave * 1024);\
    gld16(VT + (size_t)dr * S_ + (kv0) + ss,       base_ + 16384 + wave * 1024);\
    gld16(VT + (size_t)dr * S_ + (kv0) + 64 + ss,  base_ + 24576 + wave * 1024);\
} while (0)

#define WAITV0() asm volatile("s_waitcnt vmcnt(0)" ::: "memory")
#define BARRIER() do { __builtin_amdgcn_s_barrier();                           \
                       __builtin_amdgcn_sched_barrier(0); } while (0)

// exp2 + pack one 8-score chunk of A and B rows; accumulates lane-local sums
#define EXPC(cA, cB, pA, pB, hb) do {                                          \
    float a0_ = exp2fast(pA[(hb)+0]), a1_ = exp2fast(pA[(hb)+1]);              \
    float a2_ = exp2fast(pA[(hb)+2]), a3_ = exp2fast(pA[(hb)+3]);              \
    float a4_ = exp2fast(pA[(hb)+4]), a5_ = exp2fast(pA[(hb)+5]);              \
    float a6_ = exp2fast(pA[(hb)+6]), a7_ = exp2fast(pA[(hb)+7]);              \
    sA += ((a0_+a1_)+(a2_+a3_)) + ((a4_+a5_)+(a6_+a7_));                       \
    cA = u32x4{pk2(a0_,a1_), pk2(a2_,a3_), pk2(a4_,a5_), pk2(a6_,a7_)};        \
    float b0_ = exp2fast(pB[(hb)+0]), b1_ = exp2fast(pB[(hb)+1]);              \
    float b2_ = exp2fast(pB[(hb)+2]), b3_ = exp2fast(pB[(hb)+3]);              \
    float b4_ = exp2fast(pB[(hb)+4]), b5_ = exp2fast(pB[(hb)+5]);              \
    float b6_ = exp2fast(pB[(hb)+6]), b7_ = exp2fast(pB[(hb)+7]);              \
    sB += ((b0_+b1_)+(b2_+b3_)) + ((b4_+b5_)+(b6_+b7_));                       \
    cB = u32x4{pk2(b0_,b1_), pk2(b2_,b3_), pk2(b4_,b5_), pk2(b6_,b7_)};        \
} while (0)

// PV MFMA quad for one chunk (consumes cA/cB immediately)
#define PVC(ksc, cA, cB) do {                                                  \
    const int o_ = l31 * 128 + (ksc) * 32 + hi * 16;                           \
    bf16x8 v0_ = *(const bf16x8*)(vb + (o_ ^ swz));                            \
    bf16x8 v1_ = *(const bf16x8*)(vb + ((o_ + 4096) ^ swz));                   \
    bf16x8 fA_ = __builtin_bit_cast(bf16x8, cA);                               \
    bf16x8 fB_ = __builtin_bit_cast(bf16x8, cB);                               \
    __builtin_amdgcn_s_setprio(1);                                             \
    aA0 = MFMA32(v0_, fA_, aA0); aA1 = MFMA32(v1_, fA_, aA1);                  \
    aB0 = MFMA32(v0_, fB_, aB0); aB1 = MFMA32(v1_, fB_, aB1);                  \
    __builtin_amdgcn_s_setprio(0);                                             \
} while (0)

// full 128-kv compute on sub-buffer bc
#define COMP(bc) do {                                                          \
    const char* kb = pool + (bc) * 32768 + par * 8192;                         \
    const char* vb = pool + (bc) * 32768 + 16384 + par * 8192;                 \
    f32x16 p0A = {}, p1A = {}, p0B = {}, p1B = {};                             \
    _Pragma("unroll")                                                          \
    for (int ks = 0; ks < 4; ++ks) {                                           \
        const int o = l31 * 128 + ks * 32 + hi * 16;                           \
        bf16x8 k0 = *reinterpret_cast<const bf16x8*>(kb + (o ^ swz));          \
        bf16x8 k1 = *reinterpret_cast<const bf16x8*>(kb + ((o + 4096) ^ swz)); \
        __builtin_amdgcn_s_setprio(1);                                         \
        p0A = MFMA32(k0, qfA[ks], p0A);                                        \
        p1A = MFMA32(k1, qfA[ks], p1A);                                        \
        p0B = MFMA32(k0, qfB[ks], p0B);                                        \
        p1B = MFMA32(k1, qfB[ks], p1B);                                        \
        __builtin_amdgcn_s_setprio(0);                                         \
    }                                                                          \
    {                                                                          \
        u32x4 cA0, cB0, cA1, cB1, cA2, cB2, cA3, cB3;                          \
        EXPC(cA0, cB0, p0A, p0B, 0);                                           \
        PVC(0, cA0, cB0);                                                      \
        EXPC(cA1, cB1, p0A, p0B, 8);                                           \
        PVC(1, cA1, cB1);                                                      \
        EXPC(cA2, cB2, p1A, p1B, 0);                                           \
        PVC(2, cA2, cB2);                                                      \
        EXPC(cA3, cB3, p1A, p1B, 8);                                           \
        PVC(3, cA3, cB3);                                                      \
    }                                                                          \
} while (0)

__global__ __launch_bounds__(512) void attn(
    const ush* __restrict__ qg, const ush* __restrict__ kg,
    const ush* __restrict__ vtg, const float* __restrict__ hm,
    float* __restrict__ out)
{
    const int tid = threadIdx.x;
    const int wave = tid >> 6, lane = tid & 63;
    const int l31 = lane & 31, hi = lane >> 5;
    const int swz = (l31 & 7) << 4;
    const int g = blockIdx.x & 31, qt = blockIdx.x >> 5;   // XCD-local (h,bi)
    const int h = g >> 1, bi = g & 1;
    const int qsub = wave & 3, par = wave >> 2;
    const size_t ho = (size_t)(bi * H_ + h) * S_ * D_;
    const ush* Q  = qg + ho;     // [S][D], prescaled by log2(e)/8
    const ush* K  = kg + ho;     // [S][D]
    const ush* VT = vtg + ho;    // [D][S]

    __shared__ __align__(16) char pool[133120];  // 4x32K staging + 2K sums

    const int dr = wave * 8 + (lane >> 3);                          // dest row
    const int kr = (dr & ~12) | ((dr & 4) << 1) | ((dr & 8) >> 1);  // pi(dr)
    const int ss = ((lane & 7) ^ (lane >> 3)) * 8;                  // src swz

    const int q0 = qt * 256 + qsub * 64 + l31;   // qA row; qB = q0 + 32
    bf16x8 qfA[4], qfB[4];
    #pragma unroll
    for (int ks = 0; ks < 4; ++ks) {
        qfA[ks] = *reinterpret_cast<const bf16x8*>(Q + (size_t)q0 * D_ + ks * 16 + hi * 8);
        qfB[ks] = *reinterpret_cast<const bf16x8*>(Q + (size_t)(q0 + 32) * D_ + ks * 16 + hi * 8);
    }

    f32x16 aA0 = {}, aA1 = {}, aB0 = {}, aB1 = {};
    float sA = 0.f, sB = 0.f;

    // prologue: super-buffer 0 (subs 0,1) = kv 0..256
    STAGE(0, 0);
    STAGE(1, 128);
    WAITV0(); BARRIER();

    #pragma unroll 1
    for (int s = 0; s < 8; ++s) {
        if (s < 7) {
            const int nb = ((s & 1) ^ 1) * 2;     // next super-buffer subs
            STAGE(nb,     (s + 1) * 256);
            STAGE(nb + 1, (s + 1) * 256 + 128);
        }
        const int cb = (s & 1) * 2;               // current super-buffer subs
        COMP(cb);
        COMP(cb + 1);
        WAITV0(); BARRIER();
    }
    __syncthreads();   // staging pool becomes the combine scratch below

    // ---- combine across parity waves (pure addition; staging LDS is dead) --
    sA += xchg32f(sA);
    sB += xchg32f(sB);
    float* cbase = (float*)pool;
    float* lbase = (float*)(pool + 131072);

    if (par == 1) {
        #pragma unroll
        for (int c = 0; c < 4; ++c) {
            *(f32x4*)(cbase + qsub * 4096 + (0 * 4 + c) * 256 + lane * 4) =
                f32x4{aA0[c * 4], aA0[c * 4 + 1], aA0[c * 4 + 2], aA0[c * 4 + 3]};
            *(f32x4*)(cbase + qsub * 4096 + (1 * 4 + c) * 256 + lane * 4) =
                f32x4{aA1[c * 4], aA1[c * 4 + 1], aA1[c * 4 + 2], aA1[c * 4 + 3]};
            *(f32x4*)(cbase + qsub * 4096 + (2 * 4 + c) * 256 + lane * 4) =
                f32x4{aB0[c * 4], aB0[c * 4 + 1], aB0[c * 4 + 2], aB0[c * 4 + 3]};
            *(f32x4*)(cbase + qsub * 4096 + (3 * 4 + c) * 256 + lane * 4) =
                f32x4{aB1[c * 4], aB1[c * 4 + 1], aB1[c * 4 + 2], aB1[c * 4 + 3]};
        }
        lbase[qsub * 128 + lane * 2]     = sA;
        lbase[qsub * 128 + lane * 2 + 1] = sB;
    }
    __syncthreads();
    if (par == 0) {
        #pragma unroll
        for (int c = 0; c < 4; ++c) {
            f32x4 t;
            t = *(const f32x4*)(cbase + qsub * 4096 + (0 * 4 + c) * 256 + lane * 4);
            aA0[c*4] += t[0]; aA0[c*4+1] += t[1]; aA0[c*4+2] += t[2]; aA0[c*4+3] += t[3];
            t = *(const f32x4*)(cbase + qsub * 4096 + (1 * 4 + c) * 256 + lane * 4);
            aA1[c*4] += t[0]; aA1[c*4+1] += t[1]; aA1[c*4+2] += t[2]; aA1[c*4+3] += t[3];
            t = *(const f32x4*)(cbase + qsub * 4096 + (2 * 4 + c) * 256 + lane * 4);
            aB0[c*4] += t[0]; aB0[c*4+1] += t[1]; aB0[c*4+2] += t[2]; aB0[c*4+3] += t[3];
            t = *(const f32x4*)(cbase + qsub * 4096 + (3 * 4 + c) * 256 + lane * 4);
            aB1[c*4] += t[0]; aB1[c*4+1] += t[1]; aB1[c*4+2] += t[2]; aB1[c*4+3] += t[3];
        }
        const float liA = sA + lbase[qsub * 128 + lane * 2];
        const float liB = sB + lbase[qsub * 128 + lane * 2 + 1];
        const float hmv = hm[h];
        const float invA = hmv / liA, invB = hmv / liB;
        float* orA = out + ((size_t)bi * S_ + q0) * HID + h * D_;
        float* orB = out + ((size_t)bi * S_ + q0 + 32) * HID + h * D_;
        #pragma unroll
        for (int gg = 0; gg < 4; ++gg) {
            f32x4 o0, o1, o2, o3;
            #pragma unroll
            for (int e = 0; e < 4; ++e) {
                o0[e] = aA0[gg * 4 + e] * invA;
                o1[e] = aA1[gg * 4 + e] * invA;
                o2[e] = aB0[gg * 4 + e] * invB;
                o3[e] = aB1[gg * 4 + e] * invB;
            }
            *reinterpret_cast<f32x4*>(orA + gg * 8 + hi * 4)      = o0;  // d 0..31
            *reinterpret_cast<f32x4*>(orA + 32 + gg * 8 + hi * 4) = o1;  // d 32..63
            *reinterpret_cast<f32x4*>(orB + gg * 8 + hi * 4)      = o2;
            *reinterpret_cast<f32x4*>(orB + 32 + gg * 8 + hi * 4) = o3;
        }
    }
}

extern "C" void kernel_launch(void* const* d_in, const int* in_sizes, int n_in,
                              void* d_out, int out_size, void* d_ws, size_t ws_size,
                              hipStream_t stream) {
    const float* hid = (const float*)d_in[0];
    const float* hm  = (const float*)d_in[1];
    const float* Wq  = (const float*)d_in[2];
    const float* bq  = (const float*)d_in[3];
    const float* Wk  = (const float*)d_in[4];
    const float* bk  = (const float*)d_in[5];
    const float* Wv  = (const float*)d_in[6];
    const float* bv  = (const float*)d_in[7];
    float* out = (float*)d_out;

    const size_t NE = (size_t)B_ * H_ * S_ * D_;   // 4,194,304
    // d_ws: Q/K/VT bf16 = 24 MB.
    ush* qws  = (ush*)d_ws;
    ush* kws  = qws + NE;
    ush* vt   = kws + NE;
    // d_out (fully overwritten by attn at the end) hosts the prep scratch:
    // hidb (8 MB) + wt (6 MB). attn never reads d_out.
    ush* hidb = (ush*)d_out;             // B*S*HID == NE elems
    ush* wt   = hidb + NE;               // 3*HID*HID elems

    prep<<<1792, 256, 0, stream>>>(hid, hidb, Wq, Wk, Wv, wt);
    proj<<<dim3(32, 24), 256, 0, stream>>>(hidb, wt, bq, bk, bv, qws, kws, vt);
    attn<<<256, 512, 0, stream>>>(qws, kws, vt, hm, out);
}

// Round 15
// 86.616 us; speedup vs baseline: 1.4191x; 1.4191x over previous
//
#include <hip/hip_runtime.h>
#include <hip/hip_bf16.h>
#include <stdint.h>

#define B_  2
#define S_  2048
#define H_  16
#define D_  64
#define HID 1024

typedef __bf16 bf16x8 __attribute__((ext_vector_type(8)));
typedef float  f32x4  __attribute__((ext_vector_type(4)));
typedef float  f32x16 __attribute__((ext_vector_type(16)));
typedef unsigned int u32x4 __attribute__((ext_vector_type(4)));
typedef unsigned short ush;

__device__ __forceinline__ ush f2bf(float f) {
    __bf16 b = (__bf16)f;
    return __builtin_bit_cast(ush, b);
}
__device__ __forceinline__ unsigned pk2(float a, float b) {
    return (unsigned)f2bf(a) | ((unsigned)f2bf(b) << 16);
}
__device__ __forceinline__ float xchg32f(float x) {
    return __shfl_xor(x, 32, 64);
}
__device__ __forceinline__ float exp2fast(float x) {
#if __has_builtin(__builtin_amdgcn_exp2f)
    return __builtin_amdgcn_exp2f(x);
#else
    float r; asm("v_exp_f32 %0, %1" : "=v"(r) : "v"(x)); return r;
#endif
}
__device__ __forceinline__ void gld16(const void* g, void* l) {
    __builtin_amdgcn_global_load_lds(
        (const __attribute__((address_space(1))) unsigned*)g,
        (__attribute__((address_space(3))) unsigned*)l, 16, 0, 0);
}
#define MFMA32(a, b, c) __builtin_amdgcn_mfma_f32_32x32x16_bf16(a, b, c, 0, 0, 0)

// ---------------- fused prep: hidden cvt (blocks 0..1023) + W transpose -----
__global__ __launch_bounds__(256) void prep(
    const float* __restrict__ hid, ush* __restrict__ hidb,
    const float* __restrict__ Wq, const float* __restrict__ Wk,
    const float* __restrict__ Wv, ush* __restrict__ wt)
{
    const int tid = threadIdx.x;
    __shared__ ush lT[64][72];

    if (blockIdx.x < 1024) {
        size_t base = ((size_t)blockIdx.x * 256 + tid) * 16;
        #pragma unroll
        for (int half = 0; half < 2; ++half) {
            float4 v0 = *reinterpret_cast<const float4*>(hid + base + half * 8);
            float4 v1 = *reinterpret_cast<const float4*>(hid + base + half * 8 + 4);
            u32x4 o = { pk2(v0.x, v0.y), pk2(v0.z, v0.w),
                        pk2(v1.x, v1.y), pk2(v1.z, v1.w) };
            *reinterpret_cast<u32x4*>(hidb + base + half * 8) = o;
        }
        return;
    }

    const int L = blockIdx.x - 1024;            // 0..767 = 16 x 16 x 3
    const int k0 = (L & 15) * 64, n0 = ((L >> 4) & 15) * 64, sel = L >> 8;
    const float* W = sel == 0 ? Wq : (sel == 1 ? Wk : Wv);
    ush* o = wt + (size_t)sel * HID * HID;
    #pragma unroll
    for (int i = 0; i < 4; ++i) {
        int c = tid + i * 256;
        int kr = c >> 4, c4 = (c & 15) << 2;
        float4 v = *reinterpret_cast<const float4*>(W + (size_t)(k0 + kr) * HID + n0 + c4);
        lT[kr][c4 + 0] = f2bf(v.x); lT[kr][c4 + 1] = f2bf(v.y);
        lT[kr][c4 + 2] = f2bf(v.z); lT[kr][c4 + 3] = f2bf(v.w);
    }
    __syncthreads();
    #pragma unroll
    for (int i = 0; i < 2; ++i) {
        int c = tid + i * 256;
        int nr = c >> 3, k8 = (c & 7) << 3;
        ush t[8];
        #pragma unroll
        for (int u = 0; u < 8; ++u) t[u] = lT[k8 + u][nr];
        u32x4 ov = { (unsigned)t[0] | ((unsigned)t[1] << 16),
                     (unsigned)t[2] | ((unsigned)t[3] << 16),
                     (unsigned)t[4] | ((unsigned)t[5] << 16),
                     (unsigned)t[6] | ((unsigned)t[7] << 16) };
        *reinterpret_cast<u32x4*>(o + (size_t)(n0 + nr) * HID + k0 + k8) = ov;
    }
}

// ---------------- fused QKV projection: C[4096][3072] = hid_bf @ Wt^T -------
// 128x128 tile, 4 waves (2x2), BK=64, global_load_lds + XOR-swizzled LDS.
__global__ __launch_bounds__(256) void proj(
    const ush* __restrict__ hidb, const ush* __restrict__ wt,
    const float* __restrict__ bq, const float* __restrict__ bk,
    const float* __restrict__ bv,
    ush* __restrict__ qd, ush* __restrict__ kd, ush* __restrict__ vtd)
{
    const int tid = threadIdx.x;
    const int wave = tid >> 6, lane = tid & 63;
    const int fr = lane & 15, fq = lane >> 4;
    const int wr = wave >> 1, wc = wave & 1;
    const int m0 = blockIdx.x * 128;
    const int n0 = blockIdx.y * 128;            // global col in [0,3072)
    const int wsel = n0 >> 10;

    __shared__ char pool[65536];   // lA: 0 + buf*16K ; lB: 32K + buf*16K ; lT aliases

    const int cr = lane >> 3;      // row within 8-row chunk
    const int cs = lane & 7;       // 16B slot within row

    f32x4 acc[4][4] = {};

    const ush* Asrc = hidb + (size_t)m0 * HID;
    const ush* Bsrc = wt + (size_t)n0 * HID;

    auto stage = [&](int buf, int kk) {
        #pragma unroll
        for (int j = 0; j < 4; ++j) {
            int ch = wave * 4 + j;
            int r = ch * 8 + cr;
            int so = kk + ((cs ^ (r & 7)) << 3);
            gld16(Asrc + (size_t)r * HID + so, pool + buf * 16384 + ch * 1024);
            gld16(Bsrc + (size_t)r * HID + so, pool + 32768 + buf * 16384 + ch * 1024);
        }
    };

    stage(0, 0);
    __syncthreads();
    int buf = 0;
    for (int ks = 0; ks < 16; ++ks) {
        if (ks < 15) stage(buf ^ 1, (ks + 1) * 64);
        const char* ab = pool + buf * 16384;
        const char* bb = pool + 32768 + buf * 16384;
        #pragma unroll
        for (int c = 0; c < 2; ++c) {
            bf16x8 a[4], b[4];
            #pragma unroll
            for (int i = 0; i < 4; ++i) {
                int ra = wr * 64 + i * 16 + fr;
                a[i] = *reinterpret_cast<const bf16x8*>(
                    ab + ((ra * 128 + c * 64 + fq * 16) ^ ((ra & 7) << 4)));
                int rb = wc * 64 + i * 16 + fr;
                b[i] = *reinterpret_cast<const bf16x8*>(
                    bb + ((rb * 128 + c * 64 + fq * 16) ^ ((rb & 7) << 4)));
            }
            __builtin_amdgcn_s_setprio(1);
            #pragma unroll
            for (int i = 0; i < 4; ++i)
                #pragma unroll
                for (int j = 0; j < 4; ++j)
                    acc[i][j] = __builtin_amdgcn_mfma_f32_16x16x32_bf16(
                        a[i], b[j], acc[i][j], 0, 0, 0);
            __builtin_amdgcn_s_setprio(0);
        }
        __syncthreads();
        buf ^= 1;
    }

    const int bi = m0 >> 11;
    const int s0 = m0 & 2047;
    const float* bias = wsel == 0 ? bq : (wsel == 1 ? bk : bv);
    const int nb = n0 & 1023;

    if (wsel < 2) {
        ush* dst = wsel == 0 ? qd : kd;
        // Q: fold 1/sqrt(64) AND log2(e) (attn works in exp2 domain)
        const float scale = wsel == 0 ? 0.18033688011112042f : 1.0f;
        #pragma unroll
        for (int j = 0; j < 4; ++j) {
            int n = nb + wc * 64 + j * 16 + fr;
            int hh = n >> 6, d = n & 63;
            float bb2 = bias[n];
            const size_t rowb = (size_t)(bi * H_ + hh) * S_;
            #pragma unroll
            for (int i = 0; i < 4; ++i)
                #pragma unroll
                for (int e = 0; e < 4; ++e) {
                    int s = s0 + wr * 64 + i * 16 + fq * 4 + e;
                    dst[(rowb + s) * D_ + d] = f2bf((acc[i][j][e] + bb2) * scale);
                }
        }
    } else {
        // V: bounce through LDS (aliases lA/lB), store transposed [B,H,D,S]
        ush (*lT)[136] = (ush (*)[136])pool;
        #pragma unroll
        for (int j = 0; j < 4; ++j) {
            int nl = wc * 64 + j * 16 + fr;
            float bb2 = bias[nb + nl];
            #pragma unroll
            for (int i = 0; i < 4; ++i)
                #pragma unroll
                for (int e = 0; e < 4; ++e)
                    lT[wr * 64 + i * 16 + fq * 4 + e][nl] = f2bf(acc[i][j][e] + bb2);
        }
        __syncthreads();
        #pragma unroll
        for (int c2 = 0; c2 < 8; ++c2) {
            int cid = tid + c2 * 256;          // 0..2047
            int nl = cid >> 4, s8 = (cid & 15) * 8;
            int n = nb + nl, hh = n >> 6, d = n & 63;
            ush t[8];
            #pragma unroll
            for (int u = 0; u < 8; ++u) t[u] = lT[s8 + u][nl];
            u32x4 ov = { (unsigned)t[0] | ((unsigned)t[1] << 16),
                         (unsigned)t[2] | ((unsigned)t[3] << 16),
                         (unsigned)t[4] | ((unsigned)t[5] << 16),
                         (unsigned)t[6] | ((unsigned)t[7] << 16) };
            *reinterpret_cast<u32x4*>(
                vtd + ((size_t)(bi * H_ + hh) * D_ + d) * S_ + s0 + s8) = ov;
        }
    }
}

// ---------------- flash attention (r13 final, 51.4 us) ----------------------
// 3 staging buffers, counted vmcnt(4), rolled loop (#pragma unroll 1 prevents
// the cross-superstep pipelining that spills). 256 blocks (XCD decode),
// 512 thr = 8 waves = qsub(0..3) x parity(0..1), 64 q-rows/wave, kv split by
// parity, static-max exp2 softmax, pi row-permute K staging (P lane-local).
#define STAGE(sb, kv0) do {                                                    \
    char* base_ = pool + (sb) * 32768;                                         \
    gld16(K + (size_t)((kv0) + kr) * D_ + ss,      base_ + wave * 1024);       \
    gld16(K + (size_t)((kv0) + 64 + kr) * D_ + ss, base_ + 8192 + wave * 1024);\
    gld16(VT + (size_t)dr * S_ + (kv0) + ss,       base_ + 16384 + wave * 1024);\
    gld16(VT + (size_t)dr * S_ + (kv0) + 64 + ss,  base_ + 24576 + wave * 1024);\
} while (0)

#define WAITV4() asm volatile("s_waitcnt vmcnt(4)" ::: "memory")
#define WAITV0() asm volatile("s_waitcnt vmcnt(0)" ::: "memory")
#define BARRIER() do { __builtin_amdgcn_s_barrier();                           \
                       __builtin_amdgcn_sched_barrier(0); } while (0)

// exp2 + pack one 8-score chunk of A and B rows; accumulates lane-local sums
#define EXPC(cA, cB, pA, pB, hb) do {                                          \
    float a0_ = exp2fast(pA[(hb)+0]), a1_ = exp2fast(pA[(hb)+1]);              \
    float a2_ = exp2fast(pA[(hb)+2]), a3_ = exp2fast(pA[(hb)+3]);              \
    float a4_ = exp2fast(pA[(hb)+4]), a5_ = exp2fast(pA[(hb)+5]);              \
    float a6_ = exp2fast(pA[(hb)+6]), a7_ = exp2fast(pA[(hb)+7]);              \
    sA += ((a0_+a1_)+(a2_+a3_)) + ((a4_+a5_)+(a6_+a7_));                       \
    cA = u32x4{pk2(a0_,a1_), pk2(a2_,a3_), pk2(a4_,a5_), pk2(a6_,a7_)};        \
    float b0_ = exp2fast(pB[(hb)+0]), b1_ = exp2fast(pB[(hb)+1]);              \
    float b2_ = exp2fast(pB[(hb)+2]), b3_ = exp2fast(pB[(hb)+3]);              \
    float b4_ = exp2fast(pB[(hb)+4]), b5_ = exp2fast(pB[(hb)+5]);              \
    float b6_ = exp2fast(pB[(hb)+6]), b7_ = exp2fast(pB[(hb)+7]);              \
    sB += ((b0_+b1_)+(b2_+b3_)) + ((b4_+b5_)+(b6_+b7_));                       \
    cB = u32x4{pk2(b0_,b1_), pk2(b2_,b3_), pk2(b4_,b5_), pk2(b6_,b7_)};        \
} while (0)

// PV MFMA quad for one chunk (consumes cA/cB immediately)
#define PVC(ksc, cA, cB) do {                                                  \
    const int o_ = l31 * 128 + (ksc) * 32 + hi * 16;                           \
    bf16x8 v0_ = *(const bf16x8*)(vb + (o_ ^ swz));                            \
    bf16x8 v1_ = *(const bf16x8*)(vb + ((o_ + 4096) ^ swz));                   \
    bf16x8 fA_ = __builtin_bit_cast(bf16x8, cA);                               \
    bf16x8 fB_ = __builtin_bit_cast(bf16x8, cB);                               \
    __builtin_amdgcn_s_setprio(1);                                             \
    aA0 = MFMA32(v0_, fA_, aA0); aA1 = MFMA32(v1_, fA_, aA1);                  \
    aB0 = MFMA32(v0_, fB_, aB0); aB1 = MFMA32(v1_, fB_, aB1);                  \
    __builtin_amdgcn_s_setprio(0);                                             \
} while (0)

__global__ __launch_bounds__(512) void attn(
    const ush* __restrict__ qg, const ush* __restrict__ kg,
    const ush* __restrict__ vtg, const float* __restrict__ hm,
    float* __restrict__ out)
{
    const int tid = threadIdx.x;
    const int wave = tid >> 6, lane = tid & 63;
    const int l31 = lane & 31, hi = lane >> 5;
    const int swz = (l31 & 7) << 4;
    const int g = blockIdx.x & 31, qt = blockIdx.x >> 5;   // XCD-local (h,bi)
    const int h = g >> 1, bi = g & 1;
    const int qsub = wave & 3, par = wave >> 2;
    const size_t ho = (size_t)(bi * H_ + h) * S_ * D_;
    const ush* Q  = qg + ho;     // [S][D], prescaled by log2(e)/8
    const ush* K  = kg + ho;     // [S][D]
    const ush* VT = vtg + ho;    // [D][S]

    __shared__ __align__(16) char pool[100352];  // 3x32K staging + 2K sums

    const int dr = wave * 8 + (lane >> 3);                          // dest row
    const int kr = (dr & ~12) | ((dr & 4) << 1) | ((dr & 8) >> 1);  // pi(dr)
    const int ss = ((lane & 7) ^ (lane >> 3)) * 8;                  // src swz

    const int q0 = qt * 256 + qsub * 64 + l31;   // qA row; qB = q0 + 32
    bf16x8 qfA[4], qfB[4];
    #pragma unroll
    for (int ks = 0; ks < 4; ++ks) {
        qfA[ks] = *reinterpret_cast<const bf16x8*>(Q + (size_t)q0 * D_ + ks * 16 + hi * 8);
        qfB[ks] = *reinterpret_cast<const bf16x8*>(Q + (size_t)(q0 + 32) * D_ + ks * 16 + hi * 8);
    }

    f32x16 aA0 = {}, aA1 = {}, aB0 = {}, aB1 = {};
    float sA = 0.f, sB = 0.f;

    // prologue: buffers 0,1 in flight; wait only buffer 0 (4 loads outstanding)
    STAGE(0, 0);
    STAGE(1, 128);
    WAITV4(); BARRIER();

    int bc = 0;   // compute buffer for superstep s
    #pragma unroll 1
    for (int s = 0; s < 16; ++s) {
        if (s < 14) {
            int bs = bc + 2; if (bs >= 3) bs -= 3;
            STAGE(bs, (s + 2) * 128);
        }
        const char* kb = pool + bc * 32768 + par * 8192;
        const char* vb = pool + bc * 32768 + 16384 + par * 8192;

        f32x16 p0A = {}, p1A = {}, p0B = {}, p1B = {};
        #pragma unroll
        for (int ks = 0; ks < 4; ++ks) {
            const int o = l31 * 128 + ks * 32 + hi * 16;
            bf16x8 k0 = *reinterpret_cast<const bf16x8*>(kb + (o ^ swz));
            bf16x8 k1 = *reinterpret_cast<const bf16x8*>(kb + ((o + 4096) ^ swz));
            __builtin_amdgcn_s_setprio(1);
            p0A = MFMA32(k0, qfA[ks], p0A);
            p1A = MFMA32(k1, qfA[ks], p1A);
            p0B = MFMA32(k0, qfB[ks], p0B);
            p1B = MFMA32(k1, qfB[ks], p1B);
            __builtin_amdgcn_s_setprio(0);
        }

        {
            u32x4 cA0, cB0, cA1, cB1, cA2, cB2, cA3, cB3;
            EXPC(cA0, cB0, p0A, p0B, 0);
            PVC(0, cA0, cB0);
            EXPC(cA1, cB1, p0A, p0B, 8);
            PVC(1, cA1, cB1);
            EXPC(cA2, cB2, p1A, p1B, 0);
            PVC(2, cA2, cB2);
            EXPC(cA3, cB3, p1A, p1B, 8);
            PVC(3, cA3, cB3);
        }

        if (s < 14) { WAITV4(); } else { WAITV0(); }
        BARRIER();
        if (++bc == 3) bc = 0;
    }
    __syncthreads();   // staging pool becomes the combine scratch below

    // ---- combine across parity waves (pure addition; staging LDS is dead) --
    sA += xchg32f(sA);
    sB += xchg32f(sB);
    float* cbase = (float*)pool;
    float* lbase = (float*)(pool + 98304);

    if (par == 1) {
        #pragma unroll
        for (int c = 0; c < 4; ++c) {
            *(f32x4*)(cbase + qsub * 4096 + (0 * 4 + c) * 256 + lane * 4) =
                f32x4{aA0[c * 4], aA0[c * 4 + 1], aA0[c * 4 + 2], aA0[c * 4 + 3]};
            *(f32x4*)(cbase + qsub * 4096 + (1 * 4 + c) * 256 + lane * 4) =
                f32x4{aA1[c * 4], aA1[c * 4 + 1], aA1[c * 4 + 2], aA1[c * 4 + 3]};
            *(f32x4*)(cbase + qsub * 4096 + (2 * 4 + c) * 256 + lane * 4) =
                f32x4{aB0[c * 4], aB0[c * 4 + 1], aB0[c * 4 + 2], aB0[c * 4 + 3]};
            *(f32x4*)(cbase + qsub * 4096 + (3 * 4 + c) * 256 + lane * 4) =
                f32x4{aB1[c * 4], aB1[c * 4 + 1], aB1[c * 4 + 2], aB1[c * 4 + 3]};
        }
        lbase[qsub * 128 + lane * 2]     = sA;
        lbase[qsub * 128 + lane * 2 + 1] = sB;
    }
    __syncthreads();
    if (par == 0) {
        #pragma unroll
        for (int c = 0; c < 4; ++c) {
            f32x4 t;
            t = *(const f32x4*)(cbase + qsub * 4096 + (0 * 4 + c) * 256 + lane * 4);
            aA0[c*4] += t[0]; aA0[c*4+1] += t[1]; aA0[c*4+2] += t[2]; aA0[c*4+3] += t[3];
            t = *(const f32x4*)(cbase + qsub * 4096 + (1 * 4 + c) * 256 + lane * 4);
            aA1[c*4] += t[0]; aA1[c*4+1] += t[1]; aA1[c*4+2] += t[2]; aA1[c*4+3] += t[3];
            t = *(const f32x4*)(cbase + qsub * 4096 + (2 * 4 + c) * 256 + lane * 4);
            aB0[c*4] += t[0]; aB0[c*4+1] += t[1]; aB0[c*4+2] += t[2]; aB0[c*4+3] += t[3];
            t = *(const f32x4*)(cbase + qsub * 4096 + (3 * 4 + c) * 256 + lane * 4);
            aB1[c*4] += t[0]; aB1[c*4+1] += t[1]; aB1[c*4+2] += t[2]; aB1[c*4+3] += t[3];
        }
        const float liA = sA + lbase[qsub * 128 + lane * 2];
        const float liB = sB + lbase[qsub * 128 + lane * 2 + 1];
        const float hmv = hm[h];
        const float invA = hmv / liA, invB = hmv / liB;
        float* orA = out + ((size_t)bi * S_ + q0) * HID + h * D_;
        float* orB = out + ((size_t)bi * S_ + q0 + 32) * HID + h * D_;
        #pragma unroll
        for (int gg = 0; gg < 4; ++gg) {
            f32x4 o0, o1, o2, o3;
            #pragma unroll
            for (int e = 0; e < 4; ++e) {
                o0[e] = aA0[gg * 4 + e] * invA;
                o1[e] = aA1[gg * 4 + e] * invA;
                o2[e] = aB0[gg * 4 + e] * invB;
                o3[e] = aB1[gg * 4 + e] * invB;
            }
            *reinterpret_cast<f32x4*>(orA + gg * 8 + hi * 4)      = o0;  // d 0..31
            *reinterpret_cast<f32x4*>(orA + 32 + gg * 8 + hi * 4) = o1;  // d 32..63
            *reinterpret_cast<f32x4*>(orB + gg * 8 + hi * 4)      = o2;
            *reinterpret_cast<f32x4*>(orB + 32 + gg * 8 + hi * 4) = o3;
        }
    }
}

extern "C" void kernel_launch(void* const* d_in, const int* in_sizes, int n_in,
                              void* d_out, int out_size, void* d_ws, size_t ws_size,
                              hipStream_t stream) {
    const float* hid = (const float*)d_in[0];
    const float* hm  = (const float*)d_in[1];
    const float* Wq  = (const float*)d_in[2];
    const float* bq  = (const float*)d_in[3];
    const float* Wk  = (const float*)d_in[4];
    const float* bk  = (const float*)d_in[5];
    const float* Wv  = (const float*)d_in[6];
    const float* bv  = (const float*)d_in[7];
    float* out = (float*)d_out;

    const size_t NE = (size_t)B_ * H_ * S_ * D_;   // 4,194,304
    // d_ws: Q/K/VT bf16 = 24 MB.
    ush* qws  = (ush*)d_ws;
    ush* kws  = qws + NE;
    ush* vt   = kws + NE;
    // d_out (fully overwritten by attn at the end) hosts the prep scratch:
    // hidb (8 MB) + wt (6 MB). attn never reads d_out.
    ush* hidb = (ush*)d_out;             // B*S*HID == NE elems
    ush* wt   = hidb + NE;               // 3*HID*HID elems

    prep<<<1792, 256, 0, stream>>>(hid, hidb, Wq, Wk, Wv, wt);
    proj<<<dim3(32, 24), 256, 0, stream>>>(hidb, wt, bq, bk, bv, qws, kws, vt);
    attn<<<256, 512, 0, stream>>>(qws, kws, vt, hm, out);
}